// Round 10
// baseline (195.871 us; speedup 1.0000x reference)
//
#include <hip/hip_runtime.h>
#include <cfloat>
#include <math.h>

#define N_OBJ 8
#define N_PTS 2048
#define KNN   10
#define TOLC  0.01f
#define TPB   256
#define NW    4                 // waves per block = q-split factor
#define QC    (N_PTS / NW)      // 512 q's per wave
#define PC2   128               // points per block (2 per lane)
#define NCHUNK2 (N_PTS / PC2)   // 16 point-chunks per pair

// ---- order-preserving float <-> uint for atomicMin on signed floats ----
__device__ __forceinline__ unsigned int enc_f(float f) {
    unsigned int u = __float_as_uint(f);
    return (u & 0x80000000u) ? ~u : (u | 0x80000000u);
}
__device__ __forceinline__ float dec_f(unsigned int e) {
    unsigned int u = (e & 0x80000000u) ? (e & 0x7fffffffu) : ~e;
    return __uint_as_float(u);
}

// Kernel 1: per-point transform (4x4 inverse redundantly in double — closer
// to the numpy reference than fp32 adjugate; trivial cost at 64 waves).
// Writes P4=(x,y,z,|x|^2), N4=(nx,ny,nz,dot(n,x)), SD seed = enc(z).
__global__ void k_transform(const float* __restrict__ pts,
                            const float* __restrict__ T_est,
                            const float* __restrict__ T_plane,
                            float4* __restrict__ P4g,
                            float4* __restrict__ N4g,
                            unsigned int* __restrict__ SD) {
    int gid = blockIdx.x * blockDim.x + threadIdx.x;
    if (gid >= N_OBJ * N_PTS) return;
    int b = gid >> 11;

    double m[16];
#pragma unroll
    for (int i = 0; i < 16; i++) m[i] = (double)T_plane[i];
    double inv[16];
    inv[0]  =  m[5]*m[10]*m[15] - m[5]*m[11]*m[14] - m[9]*m[6]*m[15] + m[9]*m[7]*m[14] + m[13]*m[6]*m[11] - m[13]*m[7]*m[10];
    inv[4]  = -m[4]*m[10]*m[15] + m[4]*m[11]*m[14] + m[8]*m[6]*m[15] - m[8]*m[7]*m[14] - m[12]*m[6]*m[11] + m[12]*m[7]*m[10];
    inv[8]  =  m[4]*m[9]*m[15]  - m[4]*m[11]*m[13] - m[8]*m[5]*m[15] + m[8]*m[7]*m[13] + m[12]*m[5]*m[11] - m[12]*m[7]*m[9];
    inv[12] = -m[4]*m[9]*m[14]  + m[4]*m[10]*m[13] + m[8]*m[5]*m[14] - m[8]*m[6]*m[13] - m[12]*m[5]*m[10] + m[12]*m[6]*m[9];
    inv[1]  = -m[1]*m[10]*m[15] + m[1]*m[11]*m[14] + m[9]*m[2]*m[15] - m[9]*m[3]*m[14] - m[13]*m[2]*m[11] + m[13]*m[3]*m[10];
    inv[5]  =  m[0]*m[10]*m[15] - m[0]*m[11]*m[14] - m[8]*m[2]*m[15] + m[8]*m[3]*m[14] + m[12]*m[2]*m[11] - m[12]*m[3]*m[10];
    inv[9]  = -m[0]*m[9]*m[15]  + m[0]*m[11]*m[13] + m[8]*m[1]*m[15] - m[8]*m[3]*m[13] - m[12]*m[1]*m[11] + m[12]*m[3]*m[9];
    inv[13] =  m[0]*m[9]*m[14]  - m[0]*m[10]*m[13] - m[8]*m[1]*m[14] + m[8]*m[2]*m[13] + m[12]*m[1]*m[10] - m[12]*m[2]*m[9];
    inv[2]  =  m[1]*m[6]*m[15]  - m[1]*m[7]*m[14]  - m[5]*m[2]*m[15] + m[5]*m[3]*m[14] + m[13]*m[2]*m[7]  - m[13]*m[3]*m[6];
    inv[6]  = -m[0]*m[6]*m[15]  + m[0]*m[7]*m[14]  + m[4]*m[2]*m[15] - m[4]*m[3]*m[14] - m[12]*m[2]*m[7]  + m[12]*m[3]*m[6];
    inv[10] =  m[0]*m[5]*m[15]  - m[0]*m[7]*m[13]  - m[4]*m[1]*m[15] + m[4]*m[3]*m[13] + m[12]*m[1]*m[7]  - m[12]*m[3]*m[5];
    inv[14] = -m[0]*m[5]*m[14]  + m[0]*m[6]*m[13]  + m[4]*m[1]*m[14] - m[4]*m[2]*m[13] - m[12]*m[1]*m[6]  + m[12]*m[2]*m[5];
    inv[3]  = -m[1]*m[6]*m[11]  + m[1]*m[7]*m[10]  + m[5]*m[2]*m[11] - m[5]*m[3]*m[10] - m[9]*m[2]*m[7]   + m[9]*m[3]*m[6];
    inv[7]  =  m[0]*m[6]*m[11]  - m[0]*m[7]*m[10]  - m[4]*m[2]*m[11] + m[4]*m[3]*m[10] + m[8]*m[2]*m[7]   - m[8]*m[3]*m[6];
    inv[11] = -m[0]*m[5]*m[11]  + m[0]*m[7]*m[9]   + m[4]*m[1]*m[11] - m[4]*m[3]*m[9]  - m[8]*m[1]*m[7]   + m[8]*m[3]*m[5];
    inv[15] =  m[0]*m[5]*m[10]  - m[0]*m[6]*m[9]   - m[4]*m[1]*m[10] + m[4]*m[2]*m[9]  + m[8]*m[1]*m[6]   - m[8]*m[2]*m[5];
    double det  = m[0]*inv[0] + m[1]*inv[4] + m[2]*inv[8] + m[3]*inv[12];
    double rdet = 1.0 / det;

    const float* Te = T_est + b * 16;
    double M[12];
#pragma unroll
    for (int i = 0; i < 3; i++)
#pragma unroll
        for (int j = 0; j < 4; j++) {
            double s = 0.0;
#pragma unroll
            for (int kk = 0; kk < 4; kk++) s += inv[i*4+kk] * rdet * (double)Te[kk*4+j];
            M[i*4+j] = s;
        }

    const float* pp = pts + (size_t)gid * 6;
    double px = pp[0], py = pp[1], pz = pp[2];
    float nx = pp[3], ny = pp[4], nz = pp[5];
    float x = (float)(M[0]*px + M[1]*py + M[2]*pz  + M[3]);
    float y = (float)(M[4]*px + M[5]*py + M[6]*pz  + M[7]);
    float z = (float)(M[8]*px + M[9]*py + M[10]*pz + M[11]);
    float sq = fmaf(x, x, fmaf(y, y, z * z));
    float w  = fmaf(nx, x, fmaf(ny, y, nz * z));
    P4g[gid] = make_float4(x, y, z, sq);
    N4g[gid] = make_float4(nx, ny, nz, w);
    SD[gid]  = enc_f(z);   // seed min with the plane-distance term z
}

// One q against TWO points per lane: 44 VALU ops. Per-p op order IDENTICAL to
// rounds 0-9 (bit-identical numerics); p0/p1 chains interleaved for ILP.
// All q operands are VGPRs (both streams from uniform ds_read broadcast).
#define QB2(PX,PY,PZ,PW,NX,NY,NZ,NWW) \
  "v_mul_f32 %[t0], " PZ ", %[mz0]\n" \
  "v_mul_f32 %[t2], " PZ ", %[mz1]\n" \
  "v_fma_f32 %[t0], %[my0], " PY ", %[t0]\n" \
  "v_fma_f32 %[t2], %[my1], " PY ", %[t2]\n" \
  "v_fma_f32 %[t0], %[mx0], " PX ", %[t0]\n" \
  "v_fma_f32 %[t2], %[mx1], " PX ", %[t2]\n" \
  "v_add_f32 %[t0], " PW ", %[t0]\n" \
  "v_add_f32 %[t2], " PW ", %[t2]\n" \
  "v_mul_f32 %[t1], " NZ ", %[gz0]\n" \
  "v_mul_f32 %[t3], " NZ ", %[gz1]\n" \
  "v_fma_f32 %[t1], %[gy0], " NY ", %[t1]\n" \
  "v_fma_f32 %[t3], %[gy1], " NY ", %[t3]\n" \
  "v_fma_f32 %[t1], %[gx0], " NX ", %[t1]\n" \
  "v_fma_f32 %[t3], %[gx1], " NX ", %[t3]\n" \
  "v_add_f32 %[t1], " NWW ", %[t1]\n" \
  "v_add_f32 %[t3], " NWW ", %[t3]\n" \
  "v_and_b32 %[t0], -2, %[t0]\n" \
  "v_and_b32 %[t2], -2, %[t2]\n" \
  "v_cmp_lt_f32 vcc, 0, %[t1]\n" \
  "v_cndmask_b32_e64 %[t1], 0, 1, vcc\n" \
  "v_or_b32 %[t0], %[t0], %[t1]\n" \
  "v_cmp_lt_f32 vcc, 0, %[t3]\n" \
  "v_cndmask_b32_e64 %[t3], 0, 1, vcc\n" \
  "v_or_b32 %[t2], %[t2], %[t3]\n" \
  "v_med3_f32 %[d9], %[d8], %[d9], %[t0]\n" \
  "v_med3_f32 %[d8], %[d7], %[d8], %[t0]\n" \
  "v_med3_f32 %[d7], %[d6], %[d7], %[t0]\n" \
  "v_med3_f32 %[d6], %[d5], %[d6], %[t0]\n" \
  "v_med3_f32 %[d5], %[d4], %[d5], %[t0]\n" \
  "v_med3_f32 %[d4], %[d3], %[d4], %[t0]\n" \
  "v_med3_f32 %[d3], %[d2], %[d3], %[t0]\n" \
  "v_med3_f32 %[d2], %[d1], %[d2], %[t0]\n" \
  "v_med3_f32 %[d1], %[d0], %[d1], %[t0]\n" \
  "v_min_f32 %[d0], %[d0], %[t0]\n" \
  "v_med3_f32 %[e9], %[e8], %[e9], %[t2]\n" \
  "v_med3_f32 %[e8], %[e7], %[e8], %[t2]\n" \
  "v_med3_f32 %[e7], %[e6], %[e7], %[t2]\n" \
  "v_med3_f32 %[e6], %[e5], %[e6], %[t2]\n" \
  "v_med3_f32 %[e5], %[e4], %[e5], %[t2]\n" \
  "v_med3_f32 %[e4], %[e3], %[e4], %[t2]\n" \
  "v_med3_f32 %[e3], %[e2], %[e3], %[t2]\n" \
  "v_med3_f32 %[e2], %[e1], %[e2], %[t2]\n" \
  "v_med3_f32 %[e1], %[e0], %[e1], %[t2]\n" \
  "v_min_f32 %[e0], %[e0], %[t2]\n"

// One 4-q group = 8 uniform ds_read_b128 (4 P + 4 N). P at %[lb]+O*,
// N at %[lb]+32768+O* (N region sits 32KB above P in the block's LDS).
#define RDA(O0,O1,O2,O3,NO0,NO1,NO2,NO3) \
  "ds_read_b128 v[32:35], %[lb] offset:" O0 "\n" \
  "ds_read_b128 v[36:39], %[lb] offset:" O1 "\n" \
  "ds_read_b128 v[40:43], %[lb] offset:" O2 "\n" \
  "ds_read_b128 v[44:47], %[lb] offset:" O3 "\n" \
  "ds_read_b128 v[48:51], %[lb] offset:" NO0 "\n" \
  "ds_read_b128 v[52:55], %[lb] offset:" NO1 "\n" \
  "ds_read_b128 v[56:59], %[lb] offset:" NO2 "\n" \
  "ds_read_b128 v[60:63], %[lb] offset:" NO3 "\n"
#define RDB(O0,O1,O2,O3,NO0,NO1,NO2,NO3) \
  "ds_read_b128 v[64:67], %[lb] offset:" O0 "\n" \
  "ds_read_b128 v[68:71], %[lb] offset:" O1 "\n" \
  "ds_read_b128 v[72:75], %[lb] offset:" O2 "\n" \
  "ds_read_b128 v[76:79], %[lb] offset:" O3 "\n" \
  "ds_read_b128 v[80:83], %[lb] offset:" NO0 "\n" \
  "ds_read_b128 v[84:87], %[lb] offset:" NO1 "\n" \
  "ds_read_b128 v[88:91], %[lb] offset:" NO2 "\n" \
  "ds_read_b128 v[92:95], %[lb] offset:" NO3 "\n"

#define QBA \
  QB2("v32","v33","v34","v35","v48","v49","v50","v51") \
  QB2("v36","v37","v38","v39","v52","v53","v54","v55") \
  QB2("v40","v41","v42","v43","v56","v57","v58","v59") \
  QB2("v44","v45","v46","v47","v60","v61","v62","v63")
#define QBB \
  QB2("v64","v65","v66","v67","v80","v81","v82","v83") \
  QB2("v68","v69","v70","v71","v84","v85","v86","v87") \
  QB2("v72","v73","v74","v75","v88","v89","v90","v91") \
  QB2("v76","v77","v78","v79","v92","v93","v94","v95")

// Kernel 2 v10: r9's both-streams-LDS pipeline with the trip-count bug fixed
// (512 q = 128 groups of 4, loop runs 63 iters not 31) PLUS r7's proven
// 2-points-per-lane body. Why 2p is required here: a uniform ds_read_b128
// still pays the 64-lane x 16B register-writeback (>=8cy at 128B/cy return
// path — same mechanism as r5's 18cy VMEM broadcast). At 1p/lane that's
// 28.7K reads/CU x 8-12cy = 95-143us > r4's 114. At 2p/lane the read
// population halves per unit p-work: 14336 reads/CU x 8-12cy = 48-72us,
// meeting the 66us VALU floor instead of exceeding it.
//   - 896 blocks (56 pairs x 16 chunks of 128p); 4 waves/block; 64KB LDS
//     (P 32KB + N 32KB), MRG aliased; 2 blocks/CU LDS-capped
//   - counted lgkmcnt(8) between double-banked 4-q groups: DS completes
//     in-order and the in-asm queue is DS-only; prefetch distance = one
//     bank's compute (352cy at 2p) >> ~120cy DS latency even at 2 waves/SIMD
__global__ void __launch_bounds__(TPB, 2) k_pairs(const float4* __restrict__ P4g,
                                                  const float4* __restrict__ N4g,
                                                  unsigned int* __restrict__ SD) {
    __shared__ __align__(16) unsigned char shraw[2 * N_PTS * sizeof(float4)];
    float4* Pl = (float4*)shraw;                      // [2048] P of object o
    float4* Nl = (float4*)(shraw + 32768);            // [2048] N of object o
    float (*MRG)[PC2][KNN + 1] = (float (*)[PC2][KNN + 1])shraw;  // aliased

    int bx    = blockIdx.x;
    int pair  = bx >> 4;           // / NCHUNK2
    int chunk = bx & (NCHUNK2 - 1);
    int b  = pair / 7;
    int oi = pair % 7;
    int o  = oi + (oi >= b ? 1 : 0);
    int tid  = threadIdx.x;
    int lane = tid & 63;
    int wu   = __builtin_amdgcn_readfirstlane(tid >> 6);
    int p0   = chunk * PC2 + lane;
    int p1   = p0 + 64;

    // stage both streams (coalesced dwordx4 -> ds_write_b128)
    for (int i = tid; i < N_PTS; i += TPB) {
        Pl[i] = P4g[o * N_PTS + i];
        Nl[i] = N4g[o * N_PTS + i];
    }

    float4 xp0 = P4g[b * N_PTS + p0];        // per-lane points (VMEM)
    float4 xp1 = P4g[b * N_PTS + p1];
    float mx0 = -2.0f * xp0.x, my0 = -2.0f * xp0.y, mz0 = -2.0f * xp0.z;
    float gx0 = -xp0.x, gy0 = -xp0.y, gz0 = -xp0.z;
    float mx1 = -2.0f * xp1.x, my1 = -2.0f * xp1.y, mz1 = -2.0f * xp1.z;
    float gx1 = -xp1.x, gy1 = -xp1.y, gz1 = -xp1.z;

    // LDS byte offset of this wave's P window (generic LDS addr: low 32 bits
    // are the LDS offset on AMDGPU — proven in r6)
    unsigned int lb = (unsigned int)(uintptr_t)(&Pl[wu * QC]);

    const float FMAXE = __uint_as_float(0x7F7FFFFEu);   // FLT_MAX, LSB clear
    float d0_ = FMAXE, d1_ = FMAXE, d2_ = FMAXE, d3_ = FMAXE, d4_ = FMAXE;
    float d5_ = FMAXE, d6_ = FMAXE, d7_ = FMAXE, d8_ = FMAXE, d9_ = FMAXE;
    float e0_ = FMAXE, e1_ = FMAXE, e2_ = FMAXE, e3_ = FMAXE, e4_ = FMAXE;
    float e5_ = FMAXE, e6_ = FMAXE, e7_ = FMAXE, e8_ = FMAXE, e9_ = FMAXE;
    float t0, t1, t2, t3;

    __syncthreads();               // staging complete before any ds_read

    // 512 q = 128 groups of 4. Prologue loads g0->A; loop k=0..62 computes
    // g(2k),g(2k+1) while prefetching g(2k+1)->B and g(2k+2)->A; epilogue
    // does g126,g127. Counted lgkmcnt(8) = previous bank's 8 reads retired
    // (DS is in-order; queue is DS-only inside the asm).
    // Bounds: last RDB (epilogue) N offset = wu*8192 + 8064 + 32880 + 16
    //       = 65536 exactly for wu=3 -> no overrun of the 64KB allocation.
    asm volatile(
        RDA("0","16","32","48","32768","32784","32800","32816")          // g0
        "s_mov_b32 s30, 0\n"
        "Lkp%=:\n"
        RDB("64","80","96","112","32832","32848","32864","32880")        // g2k+1
        "s_waitcnt lgkmcnt(8)\n"                                         // A done
        QBA                                                              // g2k
        RDA("128","144","160","176","32896","32912","32928","32944")     // g2k+2
        "s_waitcnt lgkmcnt(8)\n"                                         // B done
        QBB                                                              // g2k+1
        "v_add_u32 %[lb], 128, %[lb]\n"
        "s_add_u32 s30, s30, 1\n"
        "s_cmp_lt_u32 s30, 63\n"
        "s_cbranch_scc1 Lkp%=\n"
        // epilogue: lb at g126 base; bank A holds g126 (issued in last iter)
        RDB("64","80","96","112","32832","32848","32864","32880")        // g127
        "s_waitcnt lgkmcnt(8)\n"
        QBA                                                              // g126
        "s_waitcnt lgkmcnt(0)\n"
        QBB                                                              // g127
        : [d0]"+v"(d0_), [d1]"+v"(d1_), [d2]"+v"(d2_), [d3]"+v"(d3_),
          [d4]"+v"(d4_), [d5]"+v"(d5_), [d6]"+v"(d6_), [d7]"+v"(d7_),
          [d8]"+v"(d8_), [d9]"+v"(d9_),
          [e0]"+v"(e0_), [e1]"+v"(e1_), [e2]"+v"(e2_), [e3]"+v"(e3_),
          [e4]"+v"(e4_), [e5]"+v"(e5_), [e6]"+v"(e6_), [e7]"+v"(e7_),
          [e8]"+v"(e8_), [e9]"+v"(e9_),
          [t0]"=&v"(t0), [t1]"=&v"(t1), [t2]"=&v"(t2), [t3]"=&v"(t3),
          [lb]"+v"(lb)
        : [mx0]"v"(mx0), [my0]"v"(my0), [mz0]"v"(mz0),
          [gx0]"v"(gx0), [gy0]"v"(gy0), [gz0]"v"(gz0),
          [mx1]"v"(mx1), [my1]"v"(my1), [mz1]"v"(mz1),
          [gx1]"v"(gx1), [gy1]"v"(gy1), [gz1]"v"(gz1)
        : "s30",
          "v32","v33","v34","v35","v36","v37","v38","v39",
          "v40","v41","v42","v43","v44","v45","v46","v47",
          "v48","v49","v50","v51","v52","v53","v54","v55",
          "v56","v57","v58","v59","v60","v61","v62","v63",
          "v64","v65","v66","v67","v68","v69","v70","v71",
          "v72","v73","v74","v75","v76","v77","v78","v79",
          "v80","v81","v82","v83","v84","v85","v86","v87",
          "v88","v89","v90","v91","v92","v93","v94","v95",
          "scc","vcc","memory");

    float td0[KNN] = {d0_, d1_, d2_, d3_, d4_, d5_, d6_, d7_, d8_, d9_};
    float td1[KNN] = {e0_, e1_, e2_, e3_, e4_, e5_, e6_, e7_, e8_, e9_};

    __syncthreads();               // all ds_reads done; safe to alias MRG
    if (wu > 0) {
#pragma unroll
        for (int j = 0; j < KNN; j++) {
            MRG[wu][lane][j]      = td0[j];
            MRG[wu][lane + 64][j] = td1[j];
        }
    }
    __syncthreads();

    if (wu == 0) {
        // merge the 3 foreign partial top-10 lists for BOTH points
        // (top-k selection is partition-invariant on the value multiset)
#pragma unroll
        for (int ww = 1; ww < NW; ww++) {
#pragma unroll
            for (int j = 0; j < KNN; j++) {
                float cp = MRG[ww][lane][j];
#pragma unroll
                for (int t = KNN - 1; t >= 1; --t)
                    td0[t] = __builtin_amdgcn_fmed3f(td0[t - 1], td0[t], cp);
                td0[0] = fminf(td0[0], cp);
                float cq = MRG[ww][lane + 64][j];
#pragma unroll
                for (int t = KNN - 1; t >= 1; --t)
                    td1[t] = __builtin_amdgcn_fmed3f(td1[t - 1], td1[t], cq);
                td1[0] = fminf(td1[0], cq);
            }
        }

        int cnt0 = 0, cnt1 = 0;
#pragma unroll
        for (int j = 0; j < KNN; j++) {
            cnt0 += (int)(__float_as_uint(td0[j]) & 1u);
            cnt1 += (int)(__float_as_uint(td1[j]) & 1u);
        }
        float dd0 = __uint_as_float(__float_as_uint(td0[0]) & 0xFFFFFFFEu) + xp0.w;
        float r0  = sqrtf(fmaxf(dd0, 0.0f));
        if (cnt0 > 8) r0 = -r0;          // sum(insides) > k*0.8 = 8 -> >= 9
        atomicMin(&SD[b * N_PTS + p0], enc_f(r0));
        float dd1 = __uint_as_float(__float_as_uint(td1[0]) & 0xFFFFFFFEu) + xp1.w;
        float r1  = sqrtf(fmaxf(dd1, 0.0f));
        if (cnt1 > 8) r1 = -r1;
        atomicMin(&SD[b * N_PTS + p1], enc_f(r1));
    }
}

// Kernel 3: decode and emit both outputs (signed_distance, then intersects
// as 0.0/1.0 floats).
__global__ void k_final(const unsigned int* __restrict__ SD,
                       float* __restrict__ out) {
    int gid = blockIdx.x * blockDim.x + threadIdx.x;
    if (gid >= N_OBJ * N_PTS) return;
    float sd = dec_f(SD[gid]);
    out[gid] = sd;
    out[N_OBJ * N_PTS + gid] = (sd < -TOLC) ? 1.0f : 0.0f;
}

extern "C" void kernel_launch(void* const* d_in, const int* in_sizes, int n_in,
                              void* d_out, int out_size, void* d_ws, size_t ws_size,
                              hipStream_t stream) {
    const float* pts     = (const float*)d_in[0];   // (8,2048,6)
    const float* T_est   = (const float*)d_in[1];   // (8,4,4)
    const float* T_plane = (const float*)d_in[2];   // (4,4)
    // d_in[3] is k == 10, hardcoded as KNN

    // workspace layout: P4 (256KB) | N4 (256KB) | SD (64KB)
    float4*       P4 = (float4*)d_ws;
    float4*       N4 = P4 + N_OBJ * N_PTS;
    unsigned int* SD = (unsigned int*)(N4 + N_OBJ * N_PTS);

    float* out = (float*)d_out;

    k_transform<<<(N_OBJ * N_PTS) / TPB, TPB, 0, stream>>>(pts, T_est, T_plane, P4, N4, SD);
    k_pairs<<<N_OBJ * (N_OBJ - 1) * NCHUNK2, TPB, 0, stream>>>(P4, N4, SD);
    k_final<<<(N_OBJ * N_PTS) / TPB, TPB, 0, stream>>>(SD, out);
}